// Round 7
// baseline (228.343 us; speedup 1.0000x reference)
//
#include <hip/hip_runtime.h>

#define BN_S 0.9999950000374997f

constexpr int BATCH = 64;

typedef __attribute__((ext_vector_type(8))) short bf16x8;
typedef __attribute__((ext_vector_type(4))) float f32x4;

__device__ __forceinline__ float bnrelu(float x, float gs, float bb) {
    return fmaxf(fmaf(x, gs, bb), 0.f);
}

__device__ __forceinline__ unsigned short f2bf(float f) {
    unsigned u = __builtin_bit_cast(unsigned, f);
    return (unsigned short)((u + 0x7FFFu + ((u >> 16) & 1u)) >> 16);
}
__device__ __forceinline__ float bf2f(unsigned short h) {
    unsigned u = ((unsigned)h) << 16;
    return __builtin_bit_cast(float, u);
}

// ================= fused block1: stem + b1c1 + b1c2 + identity sc ========
// grid (9 bands, 64 images). Per block: rows R0..R0+3 of h1.
// LDS: input band (3ch x 10 x 62) -> h0a (bnrelu1, 16ch x 8 x 62)
//      -> y1a (bnrelu2, 16ch x 6 x 62, aliased over input) -> h1 global.
__global__ __launch_bounds__(256) void b1f_k(
    const float* __restrict__ x, const float* __restrict__ w0,
    const float* __restrict__ w1, const float* __restrict__ g1v,
    const float* __restrict__ b1v, const float* __restrict__ w2,
    const float* __restrict__ g2v, const float* __restrict__ b2v,
    float* __restrict__ h1)
{
    __shared__ float uni[5952];   // input (1860) then y1a (16*6*62)
    __shared__ float h0a[7936];   // 16*8*62
    __shared__ float wst[432], w1l[2304], w2l[2304];
    __shared__ float g1l[16], b1l[16], g2l[16], b2l[16];

    const int band = blockIdx.x, b = blockIdx.y;
    const int R0 = band * 4;
    const int t = threadIdx.x;

    // ---- stage weights (layout [(ci*9+tap)*16 + co]) + bn params + input
    for (int i = t; i < 432; i += 256) {
        int co = i & 15; int tap = (i >> 4) % 9; int ci = i / 144;
        wst[i] = w0[(co * 3 + ci) * 9 + tap];
    }
    for (int i = t; i < 2304; i += 256) {
        int co = i & 15; int tap = (i >> 4) % 9; int ci = i / 144;
        w1l[i] = w1[(co * 16 + ci) * 9 + tap];
        w2l[i] = w2[(co * 16 + ci) * 9 + tap];
    }
    if (t < 16) {
        g1l[t] = g1v[t] * BN_S; b1l[t] = b1v[t];
        g2l[t] = g2v[t] * BN_S; b2l[t] = b2v[t];
    }
    for (int i = t; i < 1860; i += 256) {
        int cc = i % 62; int rr = (i / 62) % 10; int ci = i / 620;
        int gr = R0 - 3 + rr, gc = cc - 1;
        float v = 0.f;
        if (gr >= 0 && gr < 36 && gc >= 0 && gc < 60)
            v = x[((size_t)(b * 3 + ci) * 36 + gr) * 60 + gc];
        uni[i] = v;
    }
    __syncthreads();

    // ---- phase A: h0a rows 0..7 (global rows R0-2+r), bnrelu(s1_g1)
    for (int it = t; it < 384; it += 256) {
        const int cog = it / 96; int rem = it % 96;
        const int r = rem / 12; const int wc = (rem % 12) * 5;
        const int gr = R0 - 2 + r;
        float acc[5][4] = {};
        if (gr >= 0 && gr < 36) {
            for (int ci = 0; ci < 3; ++ci) {
#pragma unroll
                for (int dh = 0; dh < 3; ++dh) {
                    float aw[7];
#pragma unroll
                    for (int a = 0; a < 7; ++a) aw[a] = uni[(ci * 10 + r + dh) * 62 + wc + a];
#pragma unroll
                    for (int dw = 0; dw < 3; ++dw) {
                        const float* wp = wst + (ci * 9 + dh * 3 + dw) * 16 + cog * 4;
#pragma unroll
                        for (int c = 0; c < 4; ++c)
#pragma unroll
                            for (int j = 0; j < 5; ++j)
                                acc[j][c] = fmaf(aw[j + dw], wp[c], acc[j][c]);
                    }
                }
            }
        }
#pragma unroll
        for (int c = 0; c < 4; ++c) {
            int co = cog * 4 + c;
#pragma unroll
            for (int j = 0; j < 5; ++j) {
                float v = (gr >= 0 && gr < 36) ? bnrelu(acc[j][c], g1l[co], b1l[co]) : 0.f;
                h0a[(co * 8 + r) * 62 + wc + 1 + j] = v;
            }
        }
    }
    if (t < 256) {  // edge cols 0,61
        int co = t & 15; int r = (t >> 4) & 7; int e = t >> 7;
        h0a[(co * 8 + r) * 62 + (e ? 61 : 0)] = 0.f;
    }
    __syncthreads();

    // ---- phase B: y1a rows 0..5 (global rows R0-1+r), bnrelu(s1_g2)
    for (int it = t; it < 288; it += 256) {
        const int cog = it / 72; int rem = it % 72;
        const int r = rem / 12; const int wc = (rem % 12) * 5;
        const int gr = R0 - 1 + r;
        float acc[5][4] = {};
        if (gr >= 0 && gr < 36) {
            for (int ci = 0; ci < 16; ++ci) {
#pragma unroll
                for (int dh = 0; dh < 3; ++dh) {
                    float aw[7];
#pragma unroll
                    for (int a = 0; a < 7; ++a) aw[a] = h0a[(ci * 8 + r + dh) * 62 + wc + a];
#pragma unroll
                    for (int dw = 0; dw < 3; ++dw) {
                        const float* wp = w1l + (ci * 9 + dh * 3 + dw) * 16 + cog * 4;
#pragma unroll
                        for (int c = 0; c < 4; ++c)
#pragma unroll
                            for (int j = 0; j < 5; ++j)
                                acc[j][c] = fmaf(aw[j + dw], wp[c], acc[j][c]);
                    }
                }
            }
        }
#pragma unroll
        for (int c = 0; c < 4; ++c) {
            int co = cog * 4 + c;
#pragma unroll
            for (int j = 0; j < 5; ++j) {
                float v = (gr >= 0 && gr < 36) ? bnrelu(acc[j][c], g2l[co], b2l[co]) : 0.f;
                uni[(co * 6 + r) * 62 + wc + 1 + j] = v;
            }
        }
    }
    if (t < 192) {  // y1a edge cols
        int co = t & 15; int rem = t >> 4; int r = rem % 6; int e = rem / 6;
        uni[(co * 6 + r) * 62 + (e ? 61 : 0)] = 0.f;
    }
    __syncthreads();

    // ---- phase C: h1 rows R0..R0+3 = conv(y1a) + h0a shortcut -> global
    for (int it = t; it < 192; it += 256) {
        const int cog = it / 48; int rem = it % 48;
        const int r = rem / 12; const int wc = (rem % 12) * 5;
        const int gr = R0 + r;
        float acc[5][4] = {};
        for (int ci = 0; ci < 16; ++ci) {
#pragma unroll
            for (int dh = 0; dh < 3; ++dh) {
                float aw[7];
#pragma unroll
                for (int a = 0; a < 7; ++a) aw[a] = uni[(ci * 6 + r + dh) * 62 + wc + a];
#pragma unroll
                for (int dw = 0; dw < 3; ++dw) {
                    const float* wp = w2l + (ci * 9 + dh * 3 + dw) * 16 + cog * 4;
#pragma unroll
                    for (int c = 0; c < 4; ++c)
#pragma unroll
                        for (int j = 0; j < 5; ++j)
                            acc[j][c] = fmaf(aw[j + dw], wp[c], acc[j][c]);
                }
            }
        }
#pragma unroll
        for (int c = 0; c < 4; ++c) {
            int co = cog * 4 + c;
#pragma unroll
            for (int j = 0; j < 5; ++j) {
                float v = acc[j][c] + h0a[(co * 8 + r + 2) * 62 + wc + 1 + j];
                h1[((size_t)(b * 16 + co) * 36 + gr) * 60 + wc + j] = v;
            }
        }
    }
}

// ---------------- generic fused conv3x3 (round-5 template) ----------------
template<int CIN, int CICH, int COUT, int CO_PER, int HIN, int WIN,
         int HOUT, int WOUT, int STRIDE, int ROWS, int P, int PARTS,
         bool PRE_BN, int SC, int CSC, int SSTR, int SCPARTS>
__global__ __launch_bounds__(256) void convT_k(
    const float* __restrict__ in, size_t in_pstride,
    const float* __restrict__ w,
    const float* __restrict__ g, const float* __restrict__ bb,
    const float* __restrict__ xin, size_t xin_pstride,
    const float* __restrict__ g1v, const float* __restrict__ b1v,
    const float* __restrict__ wsc,
    float* __restrict__ out, size_t out_pstride)
{
    constexpr int IR = (STRIDE == 1) ? ROWS + 2 : 2 * ROWS + 1;
    constexpr int TW = (STRIDE == 1) ? WIN + 2 : WIN + 1;
    constexpr int AW = (P - 1) * STRIDE + 3;
    constexpr int NCOG = COUT / CO_PER;
    constexpr int PGW = WOUT / P;
    constexpr int NG = ROWS * PGW;
    constexpr int NITEMS = NG * NCOG;

    __shared__ float xs[CICH * IR * TW];
    __shared__ float wlds[CICH * 9 * COUT];
    __shared__ float g1l[SC ? CSC : 1], b1l[SC ? CSC : 1];
    __shared__ float wscl[(SC == 2) ? CSC * COUT : 1];

    const int band = blockIdx.x, b = blockIdx.y, zci = blockIdx.z;
    const int ci0 = zci * CICH;
    const int r0 = band * ROWS;
    const int r0in = r0 * STRIDE - 1;
    const int tid = threadIdx.x;

    for (int i = tid; i < CICH * 9 * COUT; i += 256) {
        int co = i % COUT; int rem = i / COUT; int tap = rem % 9; int ci = rem / 9;
        wlds[i] = w[((size_t)co * CIN + ci0 + ci) * 9 + tap];
    }
    if constexpr (SC != 0) {
        if (tid < CSC) { g1l[tid] = g1v[tid] * BN_S; b1l[tid] = b1v[tid]; }
        if constexpr (SC == 2) {
            for (int i = tid; i < CSC * COUT; i += 256) {
                int co = i % COUT; int ci = i / COUT;
                wscl[i] = wsc[(size_t)co * CSC + ci];
            }
        }
    }
    for (int i = tid; i < CICH * IR * TW; i += 256) {
        int cc = i % TW; int rem = i / TW; int rr = rem % IR; int ci = rem / IR;
        int gr = r0in + rr; int gc = cc - 1;
        float v = 0.f;
        if (gr >= 0 && gr < HIN && gc >= 0 && gc < WIN) {
            size_t off = ((size_t)(b * CIN + ci0 + ci) * HIN + gr) * WIN + gc;
            v = in[off];
            if constexpr (PARTS >= 2) v += in[off + in_pstride];
            if constexpr (PARTS >= 3) v += in[off + 2 * in_pstride];
            if constexpr (PARTS >= 4) v += in[off + 3 * in_pstride];
            if constexpr (PRE_BN) v = bnrelu(v, g[ci0 + ci] * BN_S, bb[ci0 + ci]);
        }
        xs[i] = v;
    }
    __syncthreads();

    for (int it = tid; it < NITEMS; it += 256) {
        const int cog = it / NG; const int gi = it % NG;
        const int lr = gi / PGW; const int wc = (gi % PGW) * P;
        float acc[P][CO_PER];
#pragma unroll
        for (int j = 0; j < P; ++j)
#pragma unroll
            for (int co = 0; co < CO_PER; ++co) acc[j][co] = 0.f;

        for (int ci = 0; ci < CICH; ++ci) {
            const float* xb = xs + ((ci * IR) + lr * STRIDE) * TW + wc * STRIDE;
#pragma unroll
            for (int dh = 0; dh < 3; ++dh) {
                float aw[AW];
#pragma unroll
                for (int a = 0; a < AW; ++a) aw[a] = xb[dh * TW + a];
#pragma unroll
                for (int dw = 0; dw < 3; ++dw) {
                    const float* wp = wlds + (ci * 9 + dh * 3 + dw) * COUT + cog * CO_PER;
#pragma unroll
                    for (int c4 = 0; c4 < CO_PER; c4 += 4) {
                        float4 wv = *(const float4*)(wp + c4);
#pragma unroll
                        for (int j = 0; j < P; ++j) {
                            float a_ = aw[j * STRIDE + dw];
                            acc[j][c4 + 0] = fmaf(a_, wv.x, acc[j][c4 + 0]);
                            acc[j][c4 + 1] = fmaf(a_, wv.y, acc[j][c4 + 1]);
                            acc[j][c4 + 2] = fmaf(a_, wv.z, acc[j][c4 + 2]);
                            acc[j][c4 + 3] = fmaf(a_, wv.w, acc[j][c4 + 3]);
                        }
                    }
                }
            }
        }

        if constexpr (SC == 1) {
            if (zci == 0) {
#pragma unroll
                for (int co = 0; co < CO_PER; ++co) {
                    int c = cog * CO_PER + co;
#pragma unroll
                    for (int j = 0; j < P; ++j) {
                        size_t off = ((size_t)(b * CSC + c) * HOUT + (r0 + lr)) * WOUT + wc + j;
                        float v = xin[off];
#pragma unroll
                        for (int s = 1; s < SCPARTS; ++s) v += xin[off + s * xin_pstride];
                        acc[j][co] += bnrelu(v, g1l[c], b1l[c]);
                    }
                }
            }
        }
        if constexpr (SC == 2) {
            if (zci == 0) {
                const int hix = (r0 + lr) * SSTR;
                for (int ci = 0; ci < CSC; ++ci) {
                    float vv[P];
#pragma unroll
                    for (int j = 0; j < P; ++j) {
                        size_t off = ((size_t)(b * CSC + ci) * (HOUT * SSTR) + hix) * (WOUT * SSTR)
                                     + (wc + j) * SSTR;
                        float v = xin[off];
#pragma unroll
                        for (int s = 1; s < SCPARTS; ++s) v += xin[off + s * xin_pstride];
                        vv[j] = bnrelu(v, g1l[ci], b1l[ci]);
                    }
                    const float* wp = wscl + ci * COUT + cog * CO_PER;
#pragma unroll
                    for (int c4 = 0; c4 < CO_PER; c4 += 4) {
                        float4 wv = *(const float4*)(wp + c4);
#pragma unroll
                        for (int j = 0; j < P; ++j) {
                            acc[j][c4 + 0] = fmaf(vv[j], wv.x, acc[j][c4 + 0]);
                            acc[j][c4 + 1] = fmaf(vv[j], wv.y, acc[j][c4 + 1]);
                            acc[j][c4 + 2] = fmaf(vv[j], wv.z, acc[j][c4 + 2]);
                            acc[j][c4 + 3] = fmaf(vv[j], wv.w, acc[j][c4 + 3]);
                        }
                    }
                }
            }
        }

        float* op = out + (size_t)zci * out_pstride
                    + ((size_t)(b * COUT + cog * CO_PER) * HOUT + (r0 + lr)) * WOUT + wc;
#pragma unroll
        for (int co = 0; co < CO_PER; ++co)
#pragma unroll
            for (int j = 0; j < P; ++j)
                op[(size_t)co * HOUT * WOUT + j] = acc[j][co];
    }
}

// ---------------- Wfrag prep (bf16 MFMA B-fragments per column c) --------
__global__ void f0_k(const float* __restrict__ ctw, short* __restrict__ wf)
{
    int id = blockIdx.x * 256 + threadIdx.x;   // < 196608
    int j = id & 7; int lane = (id >> 3) & 63; int tile = (id >> 9) & 3; int s = id >> 11;
    int c, ch;
    if (s < 32) { c = s; ch = 0; }
    else { c = 32 + ((s - 32) >> 1); ch = (s - 32) & 1; }
    int k = ch * 32 + ((lane >> 4) << 3) + j;
    int o = tile * 16 + (lane & 15);
    float val = 0.f;
    if (k <= c) val = ctw[o * 2080 + (k * (129 - k)) / 2 + (c - k)];
    wf[id] = (short)f2bf(val);
}

// ---------------- reduce b3c2 -> xp (4 conv partials, 2 h2 partials) -----
__global__ __launch_bounds__(256) void red_k(
    const float* __restrict__ pb, const float* __restrict__ h2,
    const float* __restrict__ g1, const float* __restrict__ b1,
    const float* __restrict__ wsc, const float* __restrict__ bng,
    const float* __restrict__ bnb, float* __restrict__ xp)
{
    __shared__ float hsc[32][136];
    __shared__ float wscl[32][16];
    __shared__ float g1l[32], b1l[32];
    const int b = blockIdx.x, cq = blockIdx.y;
    const int c0 = cq * 16;
    const int t = threadIdx.x;

    if (t < 32) { g1l[t] = g1[t] * BN_S; b1l[t] = b1[t]; }
    for (int i = t; i < 512; i += 256) {
        int ci = i & 31, cc = i >> 5;
        wscl[ci][cc] = wsc[(size_t)(c0 + cc) * 32 + ci];
    }
    __syncthreads();
    for (int i = t; i < 32 * 135; i += 256) {
        int ci = i / 135, p = i % 135;
        int hp = p / 15, wp = p % 15;
        size_t off = ((size_t)(b * 32 + ci) * 18 + hp * 2) * 30 + wp * 2;
        float v = h2[off] + h2[off + 1105920];
        hsc[ci][p] = bnrelu(v, g1l[ci], b1l[ci]);
    }
    __syncthreads();

    for (int e = t; e < 16 * 135; e += 256) {
        int cc = e / 135, p = e % 135;
        int c = c0 + cc;
        size_t idx = ((size_t)(b * 64 + c)) * 135 + p;
        float y = 0.f;
#pragma unroll
        for (int q = 0; q < 4; ++q) y += pb[idx + (size_t)q * 552960];
#pragma unroll 8
        for (int ci = 0; ci < 32; ++ci) y = fmaf(hsc[ci][p], wscl[ci][cc], y);
        xp[((size_t)b * 135 + p) * 64 + c] = bnrelu(y, bng[c] * BN_S, bnb[c]);
    }
}

// ---------------- MFMA bilinear-pooling GEMM ----------------
template<int NCH>
__device__ __forceinline__ void f2m_body(
    const unsigned short* xs, int q, const short* __restrict__ wf,
    const float* __restrict__ ctb, float* __restrict__ Abase, int p0, int t)
{
    float* A = Abase + (size_t)q * 552960;
    const int w = t >> 6, lane = t & 63;
    const int prow = w * 32;
    const int lrow = lane & 15, lk = lane >> 4;

    bf16x8 Af[2][NCH];
#pragma unroll
    for (int rt = 0; rt < 2; ++rt)
#pragma unroll
        for (int ch = 0; ch < NCH; ++ch) {
            int pix = prow + rt * 16 + lrow;
            int g = ch * 4 + lk;
            Af[rt][ch] = *(const bf16x8*)&xs[pix * 64 + ((g ^ (pix & 7)) * 8)];
        }

    f32x4 acc[2][4];
#pragma unroll
    for (int rt = 0; rt < 2; ++rt)
#pragma unroll
        for (int tt = 0; tt < 4; ++tt) acc[rt][tt] = f32x4{0.f, 0.f, 0.f, 0.f};

    const int c0 = q * 16;
    bf16x8 BA[NCH][4], BB[NCH][4];

    auto loadB = [&](int c, bf16x8 (&B)[NCH][4]) {
        int slotb = (NCH == 1) ? c : (2 * c - 32);
#pragma unroll
        for (int ch = 0; ch < NCH; ++ch) {
            const short* wb = wf + (size_t)(slotb + ch) * 2048 + lane * 8;
#pragma unroll
            for (int tt = 0; tt < 4; ++tt)
                B[ch][tt] = *(const bf16x8*)(wb + tt * 512);
        }
    };
    auto compute = [&](int c, bf16x8 (&B)[NCH][4]) {
        f32x4 S[2][4];
#pragma unroll
        for (int rt = 0; rt < 2; ++rt)
#pragma unroll
            for (int tt = 0; tt < 4; ++tt) S[rt][tt] = f32x4{0.f, 0.f, 0.f, 0.f};
#pragma unroll
        for (int ch = 0; ch < NCH; ++ch)
#pragma unroll
            for (int tt = 0; tt < 4; ++tt) {
                S[0][tt] = __builtin_amdgcn_mfma_f32_16x16x32_bf16(Af[0][ch], B[ch][tt], S[0][tt], 0, 0, 0);
                S[1][tt] = __builtin_amdgcn_mfma_f32_16x16x32_bf16(Af[1][ch], B[ch][tt], S[1][tt], 0, 0, 0);
            }
#pragma unroll
        for (int rt = 0; rt < 2; ++rt)
#pragma unroll
            for (int j = 0; j < 4; ++j) {
                int pix = prow + rt * 16 + lk * 4 + j;
                float sv = bf2f(xs[pix * 64 + (((c >> 3) ^ (pix & 7)) * 8) + (c & 7)]);
#pragma unroll
                for (int tt = 0; tt < 4; ++tt)
                    acc[rt][tt][j] += sv * S[rt][tt][j];
            }
    };

    loadB(c0, BA);
#pragma unroll 1
    for (int ci = 0; ci < 16; ci += 2) {
        loadB(c0 + ci + 1, BB);
        compute(c0 + ci, BA);
        if (ci < 14) loadB(c0 + ci + 2, BA);
        compute(c0 + ci + 1, BB);
    }

#pragma unroll
    for (int rt = 0; rt < 2; ++rt)
#pragma unroll
        for (int j = 0; j < 4; ++j) {
            int gpix = p0 + prow + rt * 16 + lk * 4 + j;
            if (gpix < 8640) {
#pragma unroll
                for (int tt = 0; tt < 4; ++tt) {
                    int o = tt * 16 + lrow;
                    float vv = acc[rt][tt][j];
                    if (q == 0) vv += ctb[o];
                    A[(size_t)gpix * 64 + o] = vv;
                }
            }
        }
}

__global__ __launch_bounds__(256) void f2m_k(
    const float* __restrict__ xp, const short* __restrict__ wf,
    const float* __restrict__ ctb, float* __restrict__ Abase)
{
    __shared__ unsigned short xs[128 * 64];
    const int t = threadIdx.x;
    const int p0 = blockIdx.x * 128;
    const int q = blockIdx.y;

    {
        int pr = t >> 1, h = t & 1;
        int gp = p0 + pr;
        float v[32];
        if (gp < 8640) {
            const float4* src = (const float4*)(xp + (size_t)gp * 64 + h * 32);
#pragma unroll
            for (int i = 0; i < 8; ++i) {
                float4 x4 = src[i];
                v[i*4+0] = x4.x; v[i*4+1] = x4.y; v[i*4+2] = x4.z; v[i*4+3] = x4.w;
            }
        } else {
#pragma unroll
            for (int i = 0; i < 32; ++i) v[i] = 0.f;
        }
#pragma unroll
        for (int g = 0; g < 4; ++g) {
            unsigned w0 = f2bf(v[g*8+0]) | ((unsigned)f2bf(v[g*8+1]) << 16);
            unsigned w1 = f2bf(v[g*8+2]) | ((unsigned)f2bf(v[g*8+3]) << 16);
            unsigned w2 = f2bf(v[g*8+4]) | ((unsigned)f2bf(v[g*8+5]) << 16);
            unsigned w3 = f2bf(v[g*8+6]) | ((unsigned)f2bf(v[g*8+7]) << 16);
            int grp = h * 4 + g;
            int sg = grp ^ (pr & 7);
            *(uint4*)&xs[pr * 64 + sg * 8] = make_uint4(w0, w1, w2, w3);
        }
    }
    __syncthreads();

    if (q < 2) f2m_body<1>(xs, q, wf, ctb, Abase, p0, t);
    else       f2m_body<2>(xs, q, wf, ctb, Abase, p0, t);
}

// ---------------- gating ----------------
__global__ void f3a_k(const float* __restrict__ A, float* __restrict__ G)
{
    int b = blockIdx.x; int t = threadIdx.x;
    int o = t & 63; int grp = t >> 6;
    float s = 0.f;
    for (int p = grp; p < 135; p += 4) {
        size_t off = ((size_t)b * 135 + p) * 64 + o;
        s += A[off] + A[off + 552960] + A[off + 2 * 552960] + A[off + 3 * 552960];
    }
    __shared__ float red[4][64];
    red[grp][o] = s;
    __syncthreads();
    if (t < 64) G[b * 64 + t] = (red[0][t] + red[1][t] + red[2][t] + red[3][t]) * (1.0f / 135.0f);
}

__global__ void f3b_k(const float* __restrict__ xp, const float* __restrict__ A,
                      const float* __restrict__ G, float* __restrict__ out)
{
    int idx = blockIdx.x * 256 + threadIdx.x;
    if (idx >= BATCH * 135 * 64) return;
    int o = idx & 63; int b = idx / (135 * 64);
    float a = A[idx] + A[idx + 552960] + A[idx + 2 * 552960] + A[idx + 3 * 552960];
    float g = G[b * 64 + o];
    float x = xp[idx];
    out[idx] = fmaf(x, a * (g + 1.f), x);
}

extern "C" void kernel_launch(void* const* d_in, const int* in_sizes, int n_in,
                              void* d_out, int out_size, void* d_ws, size_t ws_size,
                              hipStream_t stream)
{
    const float* x      = (const float*)d_in[0];
    const float* conv_w = (const float*)d_in[2];
    const float* s1_g1  = (const float*)d_in[3];
    const float* s1_b1  = (const float*)d_in[4];
    const float* s1_w1  = (const float*)d_in[5];
    const float* s1_g2  = (const float*)d_in[6];
    const float* s1_b2  = (const float*)d_in[7];
    const float* s1_w2  = (const float*)d_in[8];
    const float* s2_g1  = (const float*)d_in[9];
    const float* s2_b1  = (const float*)d_in[10];
    const float* s2_w1  = (const float*)d_in[11];
    const float* s2_g2  = (const float*)d_in[12];
    const float* s2_b2  = (const float*)d_in[13];
    const float* s2_w2  = (const float*)d_in[14];
    const float* s2_ws  = (const float*)d_in[15];
    const float* s3_g1  = (const float*)d_in[16];
    const float* s3_b1  = (const float*)d_in[17];
    const float* s3_w1  = (const float*)d_in[18];
    const float* s3_g2  = (const float*)d_in[19];
    const float* s3_b2  = (const float*)d_in[20];
    const float* s3_w2  = (const float*)d_in[21];
    const float* s3_ws  = (const float*)d_in[22];
    const float* bn_g   = (const float*)d_in[23];
    const float* bn_b   = (const float*)d_in[24];
    const float* ct_w   = (const float*)d_in[25];
    const float* ct_b   = (const float*)d_in[26];
    float* out = (float*)d_out;

    float* ws = (float*)d_ws;
    // flat, NON-overlapping region plan (floats), total ~48.9MB << ws:
    float* h1      = ws + 0;          // (64,16,36,60)      [0, 2211840)
    float* p_b2c1  = ws + 2211840;    // 2x1105920          [2211840, 4423680)
    float* p_b2c2  = ws + 4423680;    // 2x1105920 (h2)     [4423680, 6635520)
    float* p_b3c1  = ws + 6635520;    // 2x552960           [6635520, 7741440)
    float* p_b3c2  = ws + 7741440;    // 4x552960           [7741440, 9953280)
    float* xp      = ws + 9953280;    // (64,135,64)        [9953280, 10506240)
    float* A       = ws + 10506240;   // 4x552960           [10506240, 12718080)
    float* G       = ws + 12718080;   // 4096
    short* wfrag   = (short*)(ws + 12722176);  // 196608 bf16

    dim3 blk(256);

    f0_k<<<768, blk, 0, stream>>>(ct_w, wfrag);

    // fused block1: stem + b1c1 + b1c2 + identity shortcut -> h1
    b1f_k<<<dim3(9, 64), blk, 0, stream>>>(
        x, conv_w, s1_w1, s1_g1, s1_b1, s1_w2, s1_g2, s1_b2, h1);
    // b2c1: bnrelu(s2_g1) -> conv 16->32 stride2, z=2 -> grid 384
    convT_k<16, 8, 32, 4, 36, 60, 18, 30, 2, 6, 5, 1, true, 0, 1, 1, 1>
        <<<dim3(3, 64, 2), blk, 0, stream>>>(
        h1, 0, s2_w1, s2_g1, s2_b1, nullptr, 0, nullptr, nullptr, nullptr, p_b2c1, 1105920);
    // b2c2: sum2 -> conv 32->32, z=2 + 1x1 sc(h1) -> grid 384
    convT_k<32, 16, 32, 4, 18, 30, 18, 30, 1, 6, 5, 2, true, 2, 16, 2, 1>
        <<<dim3(3, 64, 2), blk, 0, stream>>>(
        p_b2c1, 1105920, s2_w2, s2_g2, s2_b2, h1, 0, s2_g1, s2_b1, s2_ws, p_b2c2, 1105920);
    // b3c1: sum2 -> conv 32->64 stride2, z=2 -> grid 384
    convT_k<32, 16, 64, 4, 18, 30, 9, 15, 2, 3, 3, 2, true, 0, 1, 1, 1>
        <<<dim3(3, 64, 2), blk, 0, stream>>>(
        p_b2c2, 1105920, s3_w1, s3_g1, s3_b1, nullptr, 0, nullptr, nullptr, nullptr, p_b3c1, 552960);
    // b3c2: sum2 -> conv 64->64, z=4 -> grid 768 (shortcut in red)
    convT_k<64, 16, 64, 4, 9, 15, 9, 15, 1, 3, 3, 2, true, 0, 1, 1, 1>
        <<<dim3(3, 64, 4), blk, 0, stream>>>(
        p_b3c1, 552960, s3_w2, s3_g2, s3_b2, nullptr, 0, nullptr, nullptr, nullptr, p_b3c2, 552960);
    // reduce: 4 conv partials + 1x1 sc(bnrelu1(sum2 h2)) + final bn -> xp
    red_k<<<dim3(64, 4), blk, 0, stream>>>(p_b3c2, p_b2c2,
                                           s3_g1, s3_b1, s3_ws, bn_g, bn_b, xp);
    // MFMA pooling GEMM: 4 c-quarters
    f2m_k<<<dim3(68, 4), blk, 0, stream>>>(xp, wfrag, ct_b, A);

    f3a_k<<<64, blk, 0, stream>>>(A, G);
    f3b_k<<<2160, blk, 0, stream>>>(xp, A, G, out);
}